// Round 2
// baseline (1552.074 us; speedup 1.0000x reference)
//
#include <hip/hip_runtime.h>
#include <hip/hip_bf16.h>
#include <math.h>

#define B 128
#define C 2048
#define N 196        // H*W = 14*14
#define K 112        // num concepts
#define KB 113       // K + background
#define ROWS 116     // 113 dist rows + 1 w_cfc row + 2 pad
#define XWROW 113
#define NCLS 200
#define CKC (C * K)  // 229376
#define RPT 29       // rows per thread (116 / 4)

// out layout (floats):
//   [0]        score_maps  B*113*196 = 2,834,944
//   [2834944]  cpt_logits  B*112     = 14,336
//   [2849280]  label_logits B*200    = 25,600
#define OUT1_OFF 2834944
#define OUT2_OFF 2849280

// ---------------------------------------------------------------------------
// Prep: build Aext[116][2048] (concepts, background, w_cfc, zeros) + a_sq
// ---------------------------------------------------------------------------
__global__ __launch_bounds__(256)
void prep_kernel(const float* __restrict__ concepts,
                 const float* __restrict__ background,
                 const float* __restrict__ wcfc,
                 float* __restrict__ Aext,
                 float* __restrict__ asq) {
    const int row = blockIdx.x;   // 0..115
    const int tid = threadIdx.x;
    const float* src = nullptr;
    if (row < K) src = concepts + (size_t)row * C;
    else if (row == K) src = background;
    else if (row == XWROW) src = wcfc;
    float local = 0.f;
    for (int i = tid; i < C; i += 256) {
        float v = src ? src[i] : 0.f;
        Aext[(size_t)row * C + i] = v;
        local += v * v;
    }
    for (int off = 32; off; off >>= 1) local += __shfl_down(local, off);
    __shared__ float red[4];
    if ((tid & 63) == 0) red[tid >> 6] = local;
    __syncthreads();
    if (tid == 0) {
        float s = red[0] + red[1] + red[2] + red[3];
        asq[row] = (row < KB) ? s : 0.f;
    }
}

// ---------------------------------------------------------------------------
// Main: per-(b, n-tile) GEMM  Aext[116,2048] @ x_b[2048, 64cols]
//       + fused per-column softmax over 113 rows + attn output
//       + per-k partial of sum_n attn*xw into logit_acc (atomic)
// block = (64, 4); grid = (4 ntiles, B)
// ---------------------------------------------------------------------------
__global__ __launch_bounds__(256)
void main_kernel(const float* __restrict__ x,
                 const float* __restrict__ Aext,
                 const float* __restrict__ asq,
                 float* __restrict__ out0,
                 float* __restrict__ logit_acc) {
    const int lane = threadIdx.x;       // 0..63 -> n within tile
    const int yg = threadIdx.y;         // 0..3  -> row group
    const int ntile = blockIdx.x;       // 0..3
    const int b = blockIdx.y;
    const int n = ntile * 64 + lane;
    const bool valid = n < N;
    const int nc = valid ? n : (N - 1);
    const int rowbase = yg * RPT;

    __shared__ float sm[ROWS][65];      // padded stride: conflict-free column reads

    const float* xp = x + (size_t)b * C * N + nc;
    float acc[RPT];
#pragma unroll
    for (int r = 0; r < RPT; ++r) acc[r] = 0.f;
    float xsq = 0.f;

    for (int c = 0; c < C; c += 4) {
        const float xv0 = xp[(size_t)(c + 0) * N];
        const float xv1 = xp[(size_t)(c + 1) * N];
        const float xv2 = xp[(size_t)(c + 2) * N];
        const float xv3 = xp[(size_t)(c + 3) * N];
        xsq += xv0 * xv0 + xv1 * xv1 + xv2 * xv2 + xv3 * xv3;
        const float* ap = Aext + c;
#pragma unroll
        for (int r = 0; r < RPT; ++r) {
            const float4 a4 = *reinterpret_cast<const float4*>(ap + (size_t)(rowbase + r) * C);
            acc[r] = fmaf(a4.x, xv0, acc[r]);
            acc[r] = fmaf(a4.y, xv1, acc[r]);
            acc[r] = fmaf(a4.z, xv2, acc[r]);
            acc[r] = fmaf(a4.w, xv3, acc[r]);
        }
    }

#pragma unroll
    for (int r = 0; r < RPT; ++r) {
        const int row = rowbase + r;
        if (row < 114) sm[row][lane] = acc[r];   // rows 0..112 dots, 113 = xw
    }
    if (yg == 0) sm[114][lane] = xsq;
    __syncthreads();

    if (yg == 0) {
        const int j = lane;
        const float xsq_j = sm[114][j];
        const float xw_j = valid ? sm[XWROW][j] : 0.f;
        float m = -3.4e38f;
        for (int k = 0; k < KB; ++k) {
            const float d2 = asq[k] + xsq_j - 2.f * sm[k][j];
            const float L = -sqrtf(fmaxf(d2, 0.f));
            sm[k][j] = L;
            m = fmaxf(m, L);
        }
        float s = 0.f;
        for (int k = 0; k < KB; ++k) {
            const float e = __expf(sm[k][j] - m);
            sm[k][j] = e;
            s += e;
        }
        const float inv = 1.f / s;
        float* o0 = out0 + (size_t)b * KB * N + n;
        for (int k = 0; k < KB; ++k) {
            const float a = sm[k][j] * inv;
            if (valid) o0[(size_t)k * N] = a;
            if (k < K) {
                float p = a * xw_j;                 // xw_j == 0 for invalid lanes
                for (int off = 32; off; off >>= 1) p += __shfl_down(p, off);
                if (lane == 0) atomicAdd(&logit_acc[b * K + k], p);
            }
        }
    }
}

// ---------------------------------------------------------------------------
// PQ: one wave per (o,k):  R[o,k] = sum_c (concepts[k,c]-modulation[c])*w_lfc[o,kC+c]
//     Qs[o,k] = sum_c modulation[c]*w_lfc[o,kC+c]
// ---------------------------------------------------------------------------
__global__ __launch_bounds__(256)
void pq_kernel(const float* __restrict__ wlfc,
               const float* __restrict__ concepts,
               const float* __restrict__ modulation,
               float* __restrict__ Rm, float* __restrict__ Qs) {
    const int wid = (blockIdx.x * 256 + threadIdx.x) >> 6;
    const int lane = threadIdx.x & 63;
    if (wid >= NCLS * K) return;
    const int o = wid / K;
    const int k = wid % K;
    const float4* wp = reinterpret_cast<const float4*>(wlfc + (size_t)o * CKC + (size_t)k * C);
    const float4* cp = reinterpret_cast<const float4*>(concepts + (size_t)k * C);
    const float4* mp = reinterpret_cast<const float4*>(modulation);
    float s1 = 0.f, s2 = 0.f;
#pragma unroll
    for (int it = 0; it < 8; ++it) {
        const int idx = it * 64 + lane;      // 512 float4 per row
        const float4 w4 = wp[idx];
        const float4 c4 = cp[idx];
        const float4 m4 = mp[idx];
        s1 += w4.x * c4.x + w4.y * c4.y + w4.z * c4.z + w4.w * c4.w;
        s2 += w4.x * m4.x + w4.y * m4.y + w4.z * m4.z + w4.w * m4.w;
    }
    for (int off = 32; off; off >>= 1) {
        s1 += __shfl_down(s1, off);
        s2 += __shfl_down(s2, off);
    }
    if (lane == 0) { Rm[wid] = s1 - s2; Qs[wid] = s2; }
}

// ---------------------------------------------------------------------------
// Final: g = sigmoid(logit_acc + b_cfc) ; label[b,o] = b_lfc[o] + sum_k g*R + Q
// ---------------------------------------------------------------------------
__global__ __launch_bounds__(256)
void final_kernel(const float* __restrict__ logit_acc,
                  const float* __restrict__ bcfc,
                  const float* __restrict__ Rm,
                  const float* __restrict__ Qs,
                  const float* __restrict__ blfc,
                  float* __restrict__ out1,
                  float* __restrict__ out2) {
    const int b = blockIdx.x;
    const int tid = threadIdx.x;
    __shared__ float g_s[K];
    if (tid < K) {
        const float v = logit_acc[b * K + tid] + bcfc[0];
        const float g = 1.f / (1.f + __expf(-v));
        out1[b * K + tid] = g;
        g_s[tid] = g;
    }
    __syncthreads();
    if (tid < NCLS) {
        float acc = blfc[tid];
        const float* rp = Rm + (size_t)tid * K;
        const float* qp = Qs + (size_t)tid * K;
        for (int k = 0; k < K; ++k) acc = fmaf(g_s[k], rp[k], acc) + qp[k];
        out2[b * NCLS + tid] = acc;
    }
}

extern "C" void kernel_launch(void* const* d_in, const int* in_sizes, int n_in,
                              void* d_out, int out_size, void* d_ws, size_t ws_size,
                              hipStream_t stream) {
    const float* x          = (const float*)d_in[0];
    const float* concepts   = (const float*)d_in[1];
    const float* modulation = (const float*)d_in[2];
    const float* background = (const float*)d_in[3];
    const float* wcfc       = (const float*)d_in[4];
    const float* bcfc       = (const float*)d_in[5];
    const float* wlfc       = (const float*)d_in[6];
    const float* blfc       = (const float*)d_in[7];

    float* out  = (float*)d_out;
    float* out0 = out;                 // [B][113][196]
    float* out1 = out + OUT1_OFF;      // [B][112]
    float* out2 = out + OUT2_OFF;      // [B][200]

    float* ws        = (float*)d_ws;
    float* Aext      = ws;                           // 116*2048 = 237568
    float* asq       = Aext + (size_t)ROWS * C;      // 128 (116 used)
    float* logit_acc = asq + 128;                    // B*K = 14336
    float* Rm        = logit_acc + B * K;            // 22400
    float* Qs        = Rm + NCLS * K;                // 22400

    hipMemsetAsync(logit_acc, 0, B * K * sizeof(float), stream);

    prep_kernel<<<ROWS, 256, 0, stream>>>(concepts, background, wcfc, Aext, asq);

    dim3 mb(64, 4);
    dim3 mg(4, B);
    main_kernel<<<mg, mb, 0, stream>>>(x, Aext, asq, out0, logit_acc);

    pq_kernel<<<(NCLS * K) / 4, 256, 0, stream>>>(wlfc, concepts, modulation, Rm, Qs);

    final_kernel<<<B, 256, 0, stream>>>(logit_acc, bcfc, Rm, Qs, blfc, out1, out2);
}

// Round 3
// 150.970 us; speedup vs baseline: 10.2807x; 10.2807x over previous
//
#include <hip/hip_runtime.h>
#include <hip/hip_bf16.h>
#include <math.h>

#define B 128
#define C 2048
#define N 196        // H*W
#define K 112
#define KB 113       // K + background
#define MROWS 128    // padded MFMA rows: 0..111 concepts, 112 bg, 113 w_cfc, 114..127 zero
#define XWROW 113
#define NCLS 200
#define CKC (C * K)
#define BKP 72       // X-tile k-stride in u16 (16B-aligned rows, conflict-measured)

#define OUT1_OFF 2834944
#define OUT2_OFF 2849280

typedef __attribute__((ext_vector_type(8))) short bf16x8;
typedef __attribute__((ext_vector_type(4))) float f32x4;

__device__ inline unsigned short f2bf(float f) {
    union { float f; unsigned u; } v; v.f = f;
    unsigned r = v.u + 0x7FFFu + ((v.u >> 16) & 1u);   // RNE
    return (unsigned short)(r >> 16);
}
__device__ inline unsigned pack2(float a, float b) {
    return (unsigned)f2bf(a) | ((unsigned)f2bf(b) << 16);
}
__device__ inline const float* row_src(int row, const float* concepts,
                                       const float* background, const float* wcfc) {
    if (row < K) return concepts + (size_t)row * C;
    if (row == K) return background;
    if (row == XWROW) return wcfc;
    return nullptr;
}

// ---------------------------------------------------------------------------
// asq_kernel: a_sq for rows 0..127 (zeros for pad rows)
// ---------------------------------------------------------------------------
__global__ __launch_bounds__(256)
void asq_kernel(const float* __restrict__ concepts, const float* __restrict__ background,
                const float* __restrict__ wcfc, float* __restrict__ asq) {
    const int row = blockIdx.x;
    const int tid = threadIdx.x;
    const float* src = row_src(row, concepts, background, wcfc);
    float local = 0.f;
    if (src) for (int i = tid; i < C; i += 256) { float v = src[i]; local += v * v; }
    for (int off = 32; off; off >>= 1) local += __shfl_down(local, off);
    __shared__ float red[4];
    if ((tid & 63) == 0) red[tid >> 6] = local;
    __syncthreads();
    if (tid == 0) asq[row] = red[0] + red[1] + red[2] + red[3];
}

// ---------------------------------------------------------------------------
// pack_kernel: A_frag[t][kw][lane][8] bf16 ; lane l holds A[16t+(l&15)][32kw+8*(l>>4)+j]
// ---------------------------------------------------------------------------
__global__ __launch_bounds__(64)
void pack_kernel(const float* __restrict__ concepts, const float* __restrict__ background,
                 const float* __restrict__ wcfc, unsigned short* __restrict__ Afrag) {
    const int t = blockIdx.x;      // 0..7 row tile
    const int kw = blockIdx.y;     // 0..63 k window
    const int l = threadIdx.x;
    const int row = 16 * t + (l & 15);
    const int kb = 32 * kw + 8 * (l >> 4);
    const float* src = row_src(row, concepts, background, wcfc);
    unsigned o[4] = {0u, 0u, 0u, 0u};
    if (src) {
        const float4 f0 = *reinterpret_cast<const float4*>(src + kb);
        const float4 f1 = *reinterpret_cast<const float4*>(src + kb + 4);
        o[0] = pack2(f0.x, f0.y); o[1] = pack2(f0.z, f0.w);
        o[2] = pack2(f1.x, f1.y); o[3] = pack2(f1.z, f1.w);
    }
    *reinterpret_cast<uint4*>(Afrag + (((size_t)t * 64 + kw) * 64 + l) * 8) =
        make_uint4(o[0], o[1], o[2], o[3]);
}

// ---------------------------------------------------------------------------
// main_kernel: per (b, ntile64): dots[128][64] = A(128x2048) @ x_b(2048x64) via MFMA
//              + fused column softmax + attn out + logit partials
// block 256 (4 waves); wave w owns row tiles {2w, 2w+1}
// ---------------------------------------------------------------------------
__global__ __launch_bounds__(256)
void main_kernel(const float* __restrict__ x,
                 const unsigned short* __restrict__ Afrag,
                 const float* __restrict__ asq_g,
                 float* __restrict__ out0,
                 float* __restrict__ lpart) {
    __shared__ __align__(16) char smem[38400];
    unsigned short* XT = (unsigned short*)smem;        // [64 n][72 k] bf16 (K-loop)
    float* dotsL = (float*)smem;                       // [128][66] f32 (epilogue)
    float* xsqp  = (float*)(smem + 33792);             // [8][64]
    float* asq_s = (float*)(smem + 35840);             // [128]
    float* pm    = (float*)(smem + 36352);             // [4][64]
    float* ps    = (float*)(smem + 37376);             // [4][64]

    const int tid = threadIdx.x;
    const int lane = tid & 63;
    const int w = tid >> 6;
    const int nt4 = blockIdx.x;
    const int b = blockIdx.y;
    const int n0 = nt4 * 64;

    // staging role: thread t covers k-chunk (t>>5) of 8, n-pair (t&31)
    const int kc = tid >> 5;
    const int pr = tid & 31;
    const int ns = n0 + 2 * pr;
    const bool v0 = ns < N, v1 = (ns + 1) < N;
    const float* xb = x + (size_t)b * C * N;

    f32x4 acc[2][4];
#pragma unroll
    for (int i = 0; i < 2; ++i)
#pragma unroll
        for (int j = 0; j < 4; ++j) acc[i][j] = (f32x4){0.f, 0.f, 0.f, 0.f};
    float xs0 = 0.f, xs1 = 0.f;

    float2 r[8];
#pragma unroll
    for (int e = 0; e < 8; ++e) {
        const float* p = xb + (size_t)(kc * 8 + e) * N + ns;
        r[e].x = v0 ? p[0] : 0.f;
        r[e].y = v1 ? p[1] : 0.f;
    }

    const int rt0 = 2 * w, rt1 = 2 * w + 1;

    for (int it = 0; it < 32; ++it) {
        __syncthreads();                       // LDS free
        unsigned w0[4], w1[4];
#pragma unroll
        for (int q = 0; q < 4; ++q) {
            const float2 ra = r[2 * q], rb = r[2 * q + 1];
            xs0 += ra.x * ra.x + rb.x * rb.x;
            xs1 += ra.y * ra.y + rb.y * rb.y;
            w0[q] = pack2(ra.x, rb.x);
            w1[q] = pack2(ra.y, rb.y);
        }
        *reinterpret_cast<uint4*>(XT + (size_t)(2 * pr) * BKP + kc * 8) =
            make_uint4(w0[0], w0[1], w0[2], w0[3]);
        *reinterpret_cast<uint4*>(XT + (size_t)(2 * pr + 1) * BKP + kc * 8) =
            make_uint4(w1[0], w1[1], w1[2], w1[3]);
        if (it < 31) {                         // T14: issue next tile's loads now
            const int kbase = (it + 1) * 64 + kc * 8;
#pragma unroll
            for (int e = 0; e < 8; ++e) {
                const float* p = xb + (size_t)(kbase + e) * N + ns;
                r[e].x = v0 ? p[0] : 0.f;
                r[e].y = v1 ? p[1] : 0.f;
            }
        }
        __syncthreads();                       // LDS ready
#pragma unroll
        for (int kw = 0; kw < 2; ++kw) {
            const bf16x8 a0 = *reinterpret_cast<const bf16x8*>(
                Afrag + (((size_t)rt0 * 64 + it * 2 + kw) * 64 + lane) * 8);
            const bf16x8 a1 = *reinterpret_cast<const bf16x8*>(
                Afrag + (((size_t)rt1 * 64 + it * 2 + kw) * 64 + lane) * 8);
#pragma unroll
            for (int nt = 0; nt < 4; ++nt) {
                const bf16x8 bv = *reinterpret_cast<const bf16x8*>(
                    XT + (size_t)(nt * 16 + (lane & 15)) * BKP + kw * 32 + (lane >> 4) * 8);
                acc[0][nt] = __builtin_amdgcn_mfma_f32_16x16x32_bf16(a0, bv, acc[0][nt], 0, 0, 0);
                acc[1][nt] = __builtin_amdgcn_mfma_f32_16x16x32_bf16(a1, bv, acc[1][nt], 0, 0, 0);
            }
        }
    }

    __syncthreads();                           // done with XT
    // acc -> dots LDS ; C/D map: col=lane&15, row=4*(lane>>4)+reg (m89-verified)
#pragma unroll
    for (int rt = 0; rt < 2; ++rt)
#pragma unroll
        for (int nt = 0; nt < 4; ++nt)
#pragma unroll
            for (int rr = 0; rr < 4; ++rr)
                dotsL[(size_t)(16 * (2 * w + rt) + 4 * (lane >> 4) + rr) * 66 +
                      nt * 16 + (lane & 15)] = acc[rt][nt][rr];
    xsqp[kc * 64 + 2 * pr] = xs0;
    xsqp[kc * 64 + 2 * pr + 1] = xs1;
    if (tid < MROWS) asq_s[tid] = asq_g[tid];
    __syncthreads();

    // softmax over rows 0..112 per column; wave q handles a row chunk
    const int j = tid & 63;
    const int q = tid >> 6;
    float xsq = 0.f;
#pragma unroll
    for (int g = 0; g < 8; ++g) xsq += xsqp[g * 64 + j];
    const int rbeg = 29 * q;
    const int rend = (rbeg + 29 < KB) ? rbeg + 29 : KB;

    float m = -3.4e38f;
    for (int row = rbeg; row < rend; ++row) {
        const float d2 = asq_s[row] + xsq - 2.f * dotsL[(size_t)row * 66 + j];
        const float L = -sqrtf(fmaxf(d2, 0.f));
        dotsL[(size_t)row * 66 + j] = L;
        m = fmaxf(m, L);
    }
    pm[q * 64 + j] = m;
    __syncthreads();
    const float M = fmaxf(fmaxf(pm[j], pm[64 + j]), fmaxf(pm[128 + j], pm[192 + j]));
    float s = 0.f;
    for (int row = rbeg; row < rend; ++row) s += __expf(dotsL[(size_t)row * 66 + j] - M);
    ps[q * 64 + j] = s;
    __syncthreads();
    const float S = ps[j] + ps[64 + j] + ps[128 + j] + ps[192 + j];
    const float invS = 1.f / S;
    const float xw = dotsL[(size_t)XWROW * 66 + j];   // raw dot row 113 (0 for pad cols)

    const bool jv = (n0 + j) < N;
    float* o0 = out0 + (size_t)b * KB * N + n0 + j;
    for (int row = rbeg; row < rend; ++row) {
        const float a = __expf(dotsL[(size_t)row * 66 + j] - M) * invS;
        if (jv) o0[(size_t)row * N] = a;
        if (row < K) {
            float p = a * xw;
            for (int off = 32; off; off >>= 1) p += __shfl_down(p, off);
            if (j == 0) lpart[((size_t)b * 4 + nt4) * K + row] = p;
        }
    }
}

// ---------------------------------------------------------------------------
// pq_kernel: R[o,k] = (concepts[k]-mod).w_lfc[o,k,:] ; Qs[o,k] = mod.w_lfc[o,k,:]
// ---------------------------------------------------------------------------
__global__ __launch_bounds__(256)
void pq_kernel(const float* __restrict__ wlfc, const float* __restrict__ concepts,
               const float* __restrict__ modulation,
               float* __restrict__ Rm, float* __restrict__ Qs) {
    const int wid = (blockIdx.x * 256 + threadIdx.x) >> 6;
    const int lane = threadIdx.x & 63;
    if (wid >= NCLS * K) return;
    const int o = wid / K;
    const int k = wid % K;
    const float4* wp = reinterpret_cast<const float4*>(wlfc + (size_t)o * CKC + (size_t)k * C);
    const float4* cp = reinterpret_cast<const float4*>(concepts + (size_t)k * C);
    const float4* mp = reinterpret_cast<const float4*>(modulation);
    float s1 = 0.f, s2 = 0.f;
#pragma unroll
    for (int it = 0; it < 8; ++it) {
        const int idx = it * 64 + lane;
        const float4 w4 = wp[idx];
        const float4 c4 = cp[idx];
        const float4 m4 = mp[idx];
        s1 += w4.x * c4.x + w4.y * c4.y + w4.z * c4.z + w4.w * c4.w;
        s2 += w4.x * m4.x + w4.y * m4.y + w4.z * m4.z + w4.w * m4.w;
    }
    for (int off = 32; off; off >>= 1) {
        s1 += __shfl_down(s1, off);
        s2 += __shfl_down(s2, off);
    }
    if (lane == 0) { Rm[wid] = s1 - s2; Qs[wid] = s2; }
}

// ---------------------------------------------------------------------------
// final_kernel: g = sigmoid(sum lpart + b_cfc); label = b_lfc + sum_k g*R + Q
// ---------------------------------------------------------------------------
__global__ __launch_bounds__(256)
void final_kernel(const float* __restrict__ lpart, const float* __restrict__ bcfc,
                  const float* __restrict__ Rm, const float* __restrict__ Qs,
                  const float* __restrict__ blfc,
                  float* __restrict__ out1, float* __restrict__ out2) {
    const int b = blockIdx.x;
    const int tid = threadIdx.x;
    __shared__ float g_s[K];
    if (tid < K) {
        const float* lp = lpart + (size_t)b * 4 * K + tid;
        const float v = lp[0] + lp[K] + lp[2 * K] + lp[3 * K] + bcfc[0];
        const float g = 1.f / (1.f + __expf(-v));
        out1[b * K + tid] = g;
        g_s[tid] = g;
    }
    __syncthreads();
    if (tid < NCLS) {
        float acc = blfc[tid];
        const float* rp = Rm + (size_t)tid * K;
        const float* qp = Qs + (size_t)tid * K;
        for (int k = 0; k < K; ++k) acc = fmaf(g_s[k], rp[k], acc) + qp[k];
        out2[b * NCLS + tid] = acc;
    }
}

extern "C" void kernel_launch(void* const* d_in, const int* in_sizes, int n_in,
                              void* d_out, int out_size, void* d_ws, size_t ws_size,
                              hipStream_t stream) {
    const float* x          = (const float*)d_in[0];
    const float* concepts   = (const float*)d_in[1];
    const float* modulation = (const float*)d_in[2];
    const float* background = (const float*)d_in[3];
    const float* wcfc       = (const float*)d_in[4];
    const float* bcfc       = (const float*)d_in[5];
    const float* wlfc       = (const float*)d_in[6];
    const float* blfc       = (const float*)d_in[7];

    float* out  = (float*)d_out;
    float* out0 = out;
    float* out1 = out + OUT1_OFF;
    float* out2 = out + OUT2_OFF;

    float* ws    = (float*)d_ws;
    float* asq   = ws;                               // 128
    float* lpart = asq + MROWS;                      // 128*4*112 = 57344
    float* Rm    = lpart + (size_t)B * 4 * K;        // 22400
    float* Qs    = Rm + NCLS * K;                    // 22400
    unsigned short* Afrag = (unsigned short*)(Qs + NCLS * K);  // 8*64*64*8 u16 = 512KB

    asq_kernel<<<MROWS, 256, 0, stream>>>(concepts, background, wcfc, asq);
    pack_kernel<<<dim3(8, 64), 64, 0, stream>>>(concepts, background, wcfc, Afrag);
    main_kernel<<<dim3(4, B), 256, 0, stream>>>(x, Afrag, asq, out0, lpart);
    pq_kernel<<<(NCLS * K) / 4, 256, 0, stream>>>(wlfc, concepts, modulation, Rm, Qs);
    final_kernel<<<B, 256, 0, stream>>>(lpart, bcfc, Rm, Qs, blfc, out1, out2);
}

// Round 4
// 137.967 us; speedup vs baseline: 11.2496x; 1.0942x over previous
//
#include <hip/hip_runtime.h>
#include <hip/hip_bf16.h>
#include <math.h>

#define B 128
#define C 2048
#define N 196        // H*W
#define K 112
#define KB 113       // K + background
#define MROWS 128    // padded MFMA rows: 0..111 concepts, 112 bg, 113 w_cfc, 114..127 zero
#define XWROW 113
#define NCLS 200
#define CKC (C * K)
#define BKP 72       // X-tile k-stride in u16 (row = 144B -> 8 lanes/bank-group, conflict-free b128)
#define NITER 32

#define OUT1_OFF 2834944
#define OUT2_OFF 2849280

typedef __attribute__((ext_vector_type(8))) short bf16x8;
typedef __attribute__((ext_vector_type(4))) float f32x4;

__device__ inline unsigned short f2bf(float f) {
    union { float f; unsigned u; } v; v.f = f;
    unsigned r = v.u + 0x7FFFu + ((v.u >> 16) & 1u);   // RNE
    return (unsigned short)(r >> 16);
}
__device__ inline unsigned pack2(float a, float b) {
    return (unsigned)f2bf(a) | ((unsigned)f2bf(b) << 16);
}
__device__ inline const float* row_src(int row, const float* concepts,
                                       const float* background, const float* wcfc) {
    if (row < K) return concepts + (size_t)row * C;
    if (row == K) return background;
    if (row == XWROW) return wcfc;
    return nullptr;
}

// ---------------------------------------------------------------------------
// asq_kernel: a_sq for rows 0..127 (zeros for pad rows)
// ---------------------------------------------------------------------------
__global__ __launch_bounds__(256)
void asq_kernel(const float* __restrict__ concepts, const float* __restrict__ background,
                const float* __restrict__ wcfc, float* __restrict__ asq) {
    const int row = blockIdx.x;
    const int tid = threadIdx.x;
    const float* src = row_src(row, concepts, background, wcfc);
    float local = 0.f;
    if (src) for (int i = tid; i < C; i += 256) { float v = src[i]; local += v * v; }
    for (int off = 32; off; off >>= 1) local += __shfl_down(local, off);
    __shared__ float red[4];
    if ((tid & 63) == 0) red[tid >> 6] = local;
    __syncthreads();
    if (tid == 0) asq[row] = red[0] + red[1] + red[2] + red[3];
}

// ---------------------------------------------------------------------------
// pack_kernel: A_frag[t][kw][lane][8] bf16 ; lane l holds A[16t+(l&15)][32kw+8*(l>>4)+j]
// ---------------------------------------------------------------------------
__global__ __launch_bounds__(64)
void pack_kernel(const float* __restrict__ concepts, const float* __restrict__ background,
                 const float* __restrict__ wcfc, unsigned short* __restrict__ Afrag) {
    const int t = blockIdx.x;      // 0..7 row tile
    const int kw = blockIdx.y;     // 0..63 k window
    const int l = threadIdx.x;
    const int row = 16 * t + (l & 15);
    const int kb = 32 * kw + 8 * (l >> 4);
    const float* src = row_src(row, concepts, background, wcfc);
    unsigned o[4] = {0u, 0u, 0u, 0u};
    if (src) {
        const float4 f0 = *reinterpret_cast<const float4*>(src + kb);
        const float4 f1 = *reinterpret_cast<const float4*>(src + kb + 4);
        o[0] = pack2(f0.x, f0.y); o[1] = pack2(f0.z, f0.w);
        o[2] = pack2(f1.x, f1.y); o[3] = pack2(f1.z, f1.w);
    }
    *reinterpret_cast<uint4*>(Afrag + (((size_t)t * 64 + kw) * 64 + l) * 8) =
        make_uint4(o[0], o[1], o[2], o[3]);
}

// ---------------------------------------------------------------------------
// main_kernel: per (b, ntile64): dots[128][64] = A(128x2048) @ x_b(2048x64) via MFMA
//   Pipelined: double-buffered XT, ONE raw s_barrier/iter (no vmcnt drain),
//   2-deep register prefetch of x, double-buffered A-frag prefetch.
// block 256 (4 waves); wave w owns row tiles {2w, 2w+1}
// ---------------------------------------------------------------------------
__global__ __launch_bounds__(256)
void main_kernel(const float* __restrict__ x,
                 const unsigned short* __restrict__ Afrag,
                 const float* __restrict__ asq_g,
                 float* __restrict__ out0,
                 float* __restrict__ lpart) {
    __shared__ __align__(16) char smem[38400];
    unsigned short* XT0 = (unsigned short*)smem;           // [64][72] bf16, buffer 0
    unsigned short* XT1 = (unsigned short*)(smem + 9216);  // buffer 1
    float* dotsL = (float*)smem;                           // epilogue overlay [128][66]
    float* xsqp  = (float*)(smem + 33792);                 // [8][64]
    float* asq_s = (float*)(smem + 35840);                 // [128]
    float* pm    = (float*)(smem + 36352);                 // [4][64]
    float* ps    = (float*)(smem + 37376);                 // [4][64]

    const int tid = threadIdx.x;
    const int lane = tid & 63;
    const int w = tid >> 6;
    const int nt4 = blockIdx.x;
    const int b = blockIdx.y;
    const int n0 = nt4 * 64;

    // staging role: thread t covers k-chunk (t>>5) of 8, n-pair (t&31)
    const int kc = tid >> 5;
    const int pr = tid & 31;
    const int ns = n0 + 2 * pr;
    const bool v0 = ns < N, v1 = (ns + 1) < N;
    const float* xb = x + (size_t)b * C * N;

    f32x4 acc[2][4];
#pragma unroll
    for (int i = 0; i < 2; ++i)
#pragma unroll
        for (int j = 0; j < 4; ++j) acc[i][j] = (f32x4){0.f, 0.f, 0.f, 0.f};
    float xs0 = 0.f, xs1 = 0.f;

#define STAGE_LOAD(R, it) do {                                                  \
        const int kb_ = (it) * 64 + kc * 8;                                     \
        _Pragma("unroll")                                                       \
        for (int e = 0; e < 8; ++e) {                                           \
            const float* p_ = xb + (size_t)(kb_ + e) * N + ns;                  \
            R[e].x = v0 ? p_[0] : 0.f;                                          \
            R[e].y = v1 ? p_[1] : 0.f;                                          \
        }                                                                       \
    } while (0)

#define LOAD_A(A, it) do {                                                      \
        _Pragma("unroll")                                                       \
        for (int rt_ = 0; rt_ < 2; ++rt_)                                       \
            _Pragma("unroll")                                                   \
            for (int kw_ = 0; kw_ < 2; ++kw_)                                   \
                A[rt_ * 2 + kw_] = *reinterpret_cast<const bf16x8*>(            \
                    Afrag + ((((size_t)(2 * w + rt_)) * 64 + (it) * 2 + kw_)    \
                             * 64 + lane) * 8);                                 \
    } while (0)

#define PACK_WRITE(R, XTB) do {                                                 \
        unsigned w0_[4], w1_[4];                                                \
        _Pragma("unroll")                                                       \
        for (int q_ = 0; q_ < 4; ++q_) {                                        \
            const float2 ra_ = R[2 * q_], rb_ = R[2 * q_ + 1];                  \
            xs0 += ra_.x * ra_.x + rb_.x * rb_.x;                               \
            xs1 += ra_.y * ra_.y + rb_.y * rb_.y;                               \
            w0_[q_] = pack2(ra_.x, rb_.x);                                      \
            w1_[q_] = pack2(ra_.y, rb_.y);                                      \
        }                                                                       \
        *reinterpret_cast<uint4*>(XTB + (size_t)(2 * pr) * BKP + kc * 8) =      \
            make_uint4(w0_[0], w0_[1], w0_[2], w0_[3]);                         \
        *reinterpret_cast<uint4*>(XTB + (size_t)(2 * pr + 1) * BKP + kc * 8) =  \
            make_uint4(w1_[0], w1_[1], w1_[2], w1_[3]);                         \
    } while (0)

#define MFMA_PHASE(A, XTB) do {                                                 \
        _Pragma("unroll")                                                       \
        for (int kw_ = 0; kw_ < 2; ++kw_) {                                     \
            _Pragma("unroll")                                                   \
            for (int nt_ = 0; nt_ < 4; ++nt_) {                                 \
                const bf16x8 bv_ = *reinterpret_cast<const bf16x8*>(            \
                    XTB + (size_t)(nt_ * 16 + (lane & 15)) * BKP                \
                        + kw_ * 32 + (lane >> 4) * 8);                          \
                acc[0][nt_] = __builtin_amdgcn_mfma_f32_16x16x32_bf16(          \
                    A[kw_], bv_, acc[0][nt_], 0, 0, 0);                         \
                acc[1][nt_] = __builtin_amdgcn_mfma_f32_16x16x32_bf16(          \
                    A[2 + kw_], bv_, acc[1][nt_], 0, 0, 0);                     \
            }                                                                   \
        }                                                                       \
    } while (0)

// raw barrier: drain LDS only (ds_writes visible), keep global loads in flight
#define BAR() do {                                                              \
        asm volatile("s_waitcnt lgkmcnt(0)" ::: "memory");                      \
        __builtin_amdgcn_s_barrier();                                           \
        __builtin_amdgcn_sched_barrier(0);                                      \
    } while (0)

    float2 rA[8], rB[8];
    bf16x8 aA[4], aB[4];
    STAGE_LOAD(rA, 0);
    STAGE_LOAD(rB, 1);
    LOAD_A(aA, 0);
    LOAD_A(aB, 1);

    for (int itp = 0; itp < 16; ++itp) {
        const int it0 = 2 * itp;
        // even iteration: buffer XT0
        PACK_WRITE(rA, XT0);
        if (it0 + 2 < NITER) STAGE_LOAD(rA, it0 + 2);
        BAR();
        MFMA_PHASE(aA, XT0);
        if (it0 + 2 < NITER) LOAD_A(aA, it0 + 2);
        // odd iteration: buffer XT1
        PACK_WRITE(rB, XT1);
        if (it0 + 3 < NITER) STAGE_LOAD(rB, it0 + 3);
        BAR();
        MFMA_PHASE(aB, XT1);
        if (it0 + 3 < NITER) LOAD_A(aB, it0 + 3);
    }

    __syncthreads();                           // full drain once; XT -> dotsL overlay
    // acc -> dots LDS ; C/D map: col=lane&15, row=4*(lane>>4)+reg (m89-verified)
#pragma unroll
    for (int rt = 0; rt < 2; ++rt)
#pragma unroll
        for (int nt = 0; nt < 4; ++nt)
#pragma unroll
            for (int rr = 0; rr < 4; ++rr)
                dotsL[(size_t)(16 * (2 * w + rt) + 4 * (lane >> 4) + rr) * 66 +
                      nt * 16 + (lane & 15)] = acc[rt][nt][rr];
    xsqp[kc * 64 + 2 * pr] = xs0;
    xsqp[kc * 64 + 2 * pr + 1] = xs1;
    if (tid < MROWS) asq_s[tid] = asq_g[tid];
    __syncthreads();

    // softmax over rows 0..112 per column; wave q handles a row chunk
    const int j = tid & 63;
    const int q = tid >> 6;
    float xsq = 0.f;
#pragma unroll
    for (int g = 0; g < 8; ++g) xsq += xsqp[g * 64 + j];
    const int rbeg = 29 * q;
    const int rend = (rbeg + 29 < KB) ? rbeg + 29 : KB;

    float m = -3.4e38f;
    for (int row = rbeg; row < rend; ++row) {
        const float d2 = asq_s[row] + xsq - 2.f * dotsL[(size_t)row * 66 + j];
        const float L = -sqrtf(fmaxf(d2, 0.f));
        dotsL[(size_t)row * 66 + j] = L;
        m = fmaxf(m, L);
    }
    pm[q * 64 + j] = m;
    __syncthreads();
    const float M = fmaxf(fmaxf(pm[j], pm[64 + j]), fmaxf(pm[128 + j], pm[192 + j]));
    float s = 0.f;
    for (int row = rbeg; row < rend; ++row) s += __expf(dotsL[(size_t)row * 66 + j] - M);
    ps[q * 64 + j] = s;
    __syncthreads();
    const float S = ps[j] + ps[64 + j] + ps[128 + j] + ps[192 + j];
    const float invS = 1.f / S;
    const float xw = dotsL[(size_t)XWROW * 66 + j];   // raw dot row 113

    const bool jv = (n0 + j) < N;
    float* o0 = out0 + (size_t)b * KB * N + n0 + j;
    for (int row = rbeg; row < rend; ++row) {
        const float a = __expf(dotsL[(size_t)row * 66 + j] - M) * invS;
        if (jv) o0[(size_t)row * N] = a;
        if (row < K) {
            float p = a * xw;
            for (int off = 32; off; off >>= 1) p += __shfl_down(p, off);
            if (j == 0) lpart[((size_t)b * 4 + nt4) * K + row] = p;
        }
    }
}

// ---------------------------------------------------------------------------
// pq_kernel: R[o,k] = (concepts[k]-mod).w_lfc[o,k,:] ; Qs[o,k] = mod.w_lfc[o,k,:]
// ---------------------------------------------------------------------------
__global__ __launch_bounds__(256)
void pq_kernel(const float* __restrict__ wlfc, const float* __restrict__ concepts,
               const float* __restrict__ modulation,
               float* __restrict__ Rm, float* __restrict__ Qs) {
    const int wid = (blockIdx.x * 256 + threadIdx.x) >> 6;
    const int lane = threadIdx.x & 63;
    if (wid >= NCLS * K) return;
    const int o = wid / K;
    const int k = wid % K;
    const float4* wp = reinterpret_cast<const float4*>(wlfc + (size_t)o * CKC + (size_t)k * C);
    const float4* cp = reinterpret_cast<const float4*>(concepts + (size_t)k * C);
    const float4* mp = reinterpret_cast<const float4*>(modulation);
    float s1 = 0.f, s2 = 0.f;
#pragma unroll
    for (int it = 0; it < 8; ++it) {
        const int idx = it * 64 + lane;
        const float4 w4 = wp[idx];
        const float4 c4 = cp[idx];
        const float4 m4 = mp[idx];
        s1 += w4.x * c4.x + w4.y * c4.y + w4.z * c4.z + w4.w * c4.w;
        s2 += w4.x * m4.x + w4.y * m4.y + w4.z * m4.z + w4.w * m4.w;
    }
    for (int off = 32; off; off >>= 1) {
        s1 += __shfl_down(s1, off);
        s2 += __shfl_down(s2, off);
    }
    if (lane == 0) { Rm[wid] = s1 - s2; Qs[wid] = s2; }
}

// ---------------------------------------------------------------------------
// final_kernel: g = sigmoid(sum lpart + b_cfc); label = b_lfc + sum_k g*R + Q
// ---------------------------------------------------------------------------
__global__ __launch_bounds__(256)
void final_kernel(const float* __restrict__ lpart, const float* __restrict__ bcfc,
                  const float* __restrict__ Rm, const float* __restrict__ Qs,
                  const float* __restrict__ blfc,
                  float* __restrict__ out1, float* __restrict__ out2) {
    const int b = blockIdx.x;
    const int tid = threadIdx.x;
    __shared__ float g_s[K];
    if (tid < K) {
        const float* lp = lpart + (size_t)b * 4 * K + tid;
        const float v = lp[0] + lp[K] + lp[2 * K] + lp[3 * K] + bcfc[0];
        const float g = 1.f / (1.f + __expf(-v));
        out1[b * K + tid] = g;
        g_s[tid] = g;
    }
    __syncthreads();
    if (tid < NCLS) {
        float acc = blfc[tid];
        const float* rp = Rm + (size_t)tid * K;
        const float* qp = Qs + (size_t)tid * K;
        for (int k = 0; k < K; ++k) acc = fmaf(g_s[k], rp[k], acc) + qp[k];
        out2[b * NCLS + tid] = acc;
    }
}

extern "C" void kernel_launch(void* const* d_in, const int* in_sizes, int n_in,
                              void* d_out, int out_size, void* d_ws, size_t ws_size,
                              hipStream_t stream) {
    const float* x          = (const float*)d_in[0];
    const float* concepts   = (const float*)d_in[1];
    const float* modulation = (const float*)d_in[2];
    const float* background = (const float*)d_in[3];
    const float* wcfc       = (const float*)d_in[4];
    const float* bcfc       = (const float*)d_in[5];
    const float* wlfc       = (const float*)d_in[6];
    const float* blfc       = (const float*)d_in[7];

    float* out  = (float*)d_out;
    float* out0 = out;
    float* out1 = out + OUT1_OFF;
    float* out2 = out + OUT2_OFF;

    float* ws    = (float*)d_ws;
    float* asq   = ws;                               // 128
    float* lpart = asq + MROWS;                      // 128*4*112 = 57344
    float* Rm    = lpart + (size_t)B * 4 * K;        // 22400
    float* Qs    = Rm + NCLS * K;                    // 22400
    unsigned short* Afrag = (unsigned short*)(Qs + NCLS * K);  // 8*64*64*8 u16 = 512KB

    asq_kernel<<<MROWS, 256, 0, stream>>>(concepts, background, wcfc, asq);
    pack_kernel<<<dim3(8, 64), 64, 0, stream>>>(concepts, background, wcfc, Afrag);
    main_kernel<<<dim3(4, B), 256, 0, stream>>>(x, Afrag, asq, out0, lpart);
    pq_kernel<<<(NCLS * K) / 4, 256, 0, stream>>>(wlfc, concepts, modulation, Rm, Qs);
    final_kernel<<<B, 256, 0, stream>>>(lpart, bcfc, Rm, Qs, blfc, out1, out2);
}

// Round 5
// 127.465 us; speedup vs baseline: 12.1764x; 1.0824x over previous
//
#include <hip/hip_runtime.h>
#include <hip/hip_bf16.h>
#include <math.h>

#define B 128
#define C 2048
#define N 196        // H*W
#define K 112
#define KB 113       // K + background
#define MROWS 128    // padded MFMA rows: 0..111 concepts, 112 bg, 113 w_cfc, 114..127 zero
#define XWROW 113
#define NCLS 200
#define CKC (C * K)
#define BKP 72       // X-tile k-stride in u16 (row = 144B -> conflict-free b128)
#define NITER 32

#define OUT1_OFF 2834944
#define OUT2_OFF 2849280

typedef __attribute__((ext_vector_type(8))) short bf16x8;
typedef __attribute__((ext_vector_type(4))) float f32x4;

__device__ inline unsigned short f2bf(float f) {
    union { float f; unsigned u; } v; v.f = f;
    unsigned r = v.u + 0x7FFFu + ((v.u >> 16) & 1u);   // RNE
    return (unsigned short)(r >> 16);
}
__device__ inline unsigned pack2(float a, float b) {
    return (unsigned)f2bf(a) | ((unsigned)f2bf(b) << 16);
}
__device__ inline const float* row_src(int row, const float* concepts,
                                       const float* background, const float* wcfc) {
    if (row < K) return concepts + (size_t)row * C;
    if (row == K) return background;
    if (row == XWROW) return wcfc;
    return nullptr;
}

// ---------------------------------------------------------------------------
// asq_kernel: a_sq for rows 0..127 (zeros for pad rows)
// ---------------------------------------------------------------------------
__global__ __launch_bounds__(256)
void asq_kernel(const float* __restrict__ concepts, const float* __restrict__ background,
                const float* __restrict__ wcfc, float* __restrict__ asq) {
    const int row = blockIdx.x;
    const int tid = threadIdx.x;
    const float* src = row_src(row, concepts, background, wcfc);
    float local = 0.f;
    if (src) for (int i = tid; i < C; i += 256) { float v = src[i]; local += v * v; }
    for (int off = 32; off; off >>= 1) local += __shfl_down(local, off);
    __shared__ float red[4];
    if ((tid & 63) == 0) red[tid >> 6] = local;
    __syncthreads();
    if (tid == 0) asq[row] = red[0] + red[1] + red[2] + red[3];
}

// ---------------------------------------------------------------------------
// pack_kernel: A_frag[t][kw][lane][8] bf16 ; lane l holds A[16t+(l&15)][32kw+8*(l>>4)+j]
// ---------------------------------------------------------------------------
__global__ __launch_bounds__(64)
void pack_kernel(const float* __restrict__ concepts, const float* __restrict__ background,
                 const float* __restrict__ wcfc, unsigned short* __restrict__ Afrag) {
    const int t = blockIdx.x;      // 0..7 row tile
    const int kw = blockIdx.y;     // 0..63 k window
    const int l = threadIdx.x;
    const int row = 16 * t + (l & 15);
    const int kb = 32 * kw + 8 * (l >> 4);
    const float* src = row_src(row, concepts, background, wcfc);
    unsigned o[4] = {0u, 0u, 0u, 0u};
    if (src) {
        const float4 f0 = *reinterpret_cast<const float4*>(src + kb);
        const float4 f1 = *reinterpret_cast<const float4*>(src + kb + 4);
        o[0] = pack2(f0.x, f0.y); o[1] = pack2(f0.z, f0.w);
        o[2] = pack2(f1.x, f1.y); o[3] = pack2(f1.z, f1.w);
    }
    *reinterpret_cast<uint4*>(Afrag + (((size_t)t * 64 + kw) * 64 + l) * 8) =
        make_uint4(o[0], o[1], o[2], o[3]);
}

// ---------------------------------------------------------------------------
// main_kernel: per (b, ntile64): dots[128][64] = A(128x2048) @ x_b(2048x64) via MFMA
//   Pipelined: double-buffered XT, ONE raw s_barrier/iter, 2-deep register
//   prefetch of x with PURE loads (clamped addresses, no cndmask on load
//   results; n>=N zeroing applied via AND-mask at the pack/consume site).
// block 256 (4 waves); wave w owns row tiles {2w, 2w+1}
// ---------------------------------------------------------------------------
__global__ __launch_bounds__(256)
void main_kernel(const float* __restrict__ x,
                 const unsigned short* __restrict__ Afrag,
                 const float* __restrict__ asq_g,
                 float* __restrict__ out0,
                 float* __restrict__ lpart) {
    __shared__ __align__(16) char smem[38400];
    unsigned short* XT0 = (unsigned short*)smem;           // [64][72] bf16, buffer 0
    unsigned short* XT1 = (unsigned short*)(smem + 9216);  // buffer 1
    float* dotsL = (float*)smem;                           // epilogue overlay [128][66]
    float* xsqp  = (float*)(smem + 33792);                 // [8][64]
    float* asq_s = (float*)(smem + 35840);                 // [128]
    float* pm    = (float*)(smem + 36352);                 // [4][64]
    float* ps    = (float*)(smem + 37376);                 // [4][64]

    const int tid = threadIdx.x;
    const int lane = tid & 63;
    const int w = tid >> 6;
    const int nt4 = blockIdx.x;
    const int b = blockIdx.y;
    const int n0 = nt4 * 64;

    // staging role: thread t covers k-chunk (t>>5) of 8, n-pair (t&31)
    const int kc = tid >> 5;
    const int pr = tid & 31;
    const int ns = n0 + 2 * pr;
    const bool v0 = ns < N, v1 = (ns + 1) < N;
    const unsigned mA = v0 ? 0xFFFFFFFFu : 0u;   // zero-mask for packed n=ns words
    const unsigned mB = v1 ? 0xFFFFFFFFu : 0u;   // zero-mask for packed n=ns+1 words
    const int nsc = (ns < N - 2) ? ns : (N - 2); // clamped, always-valid column pair
    const float* xcl = x + (size_t)b * C * N + nsc;

    f32x4 acc[2][4];
#pragma unroll
    for (int i = 0; i < 2; ++i)
#pragma unroll
        for (int j = 0; j < 4; ++j) acc[i][j] = (f32x4){0.f, 0.f, 0.f, 0.f};
    float xs0 = 0.f, xs1 = 0.f;

// pure loads — no conditionals on results; batched, prefetch-friendly
#define STAGE_LOAD(R, it) do {                                                  \
        const float* pb_ = xcl + (size_t)((it) * 64 + kc * 8) * N;              \
        _Pragma("unroll")                                                       \
        for (int e = 0; e < 8; ++e)                                             \
            R[e] = *reinterpret_cast<const float2*>(pb_ + (size_t)e * N);       \
    } while (0)

#define LOAD_A(A, it) do {                                                      \
        _Pragma("unroll")                                                       \
        for (int rt_ = 0; rt_ < 2; ++rt_)                                       \
            _Pragma("unroll")                                                   \
            for (int kw_ = 0; kw_ < 2; ++kw_)                                   \
                A[rt_ * 2 + kw_] = *reinterpret_cast<const bf16x8*>(            \
                    Afrag + ((((size_t)(2 * w + rt_)) * 64 + (it) * 2 + kw_)    \
                             * 64 + lane) * 8);                                 \
    } while (0)

#define PACK_WRITE(R, XTB) do {                                                 \
        unsigned w0_[4], w1_[4];                                                \
        _Pragma("unroll")                                                       \
        for (int q_ = 0; q_ < 4; ++q_) {                                        \
            const float2 ra_ = R[2 * q_], rb_ = R[2 * q_ + 1];                  \
            xs0 += ra_.x * ra_.x + rb_.x * rb_.x;                               \
            xs1 += ra_.y * ra_.y + rb_.y * rb_.y;                               \
            w0_[q_] = pack2(ra_.x, rb_.x) & mA;                                 \
            w1_[q_] = pack2(ra_.y, rb_.y) & mB;                                 \
        }                                                                       \
        *reinterpret_cast<uint4*>(XTB + (size_t)(2 * pr) * BKP + kc * 8) =      \
            make_uint4(w0_[0], w0_[1], w0_[2], w0_[3]);                         \
        *reinterpret_cast<uint4*>(XTB + (size_t)(2 * pr + 1) * BKP + kc * 8) =  \
            make_uint4(w1_[0], w1_[1], w1_[2], w1_[3]);                         \
    } while (0)

#define MFMA_PHASE(A, XTB) do {                                                 \
        _Pragma("unroll")                                                       \
        for (int kw_ = 0; kw_ < 2; ++kw_) {                                     \
            _Pragma("unroll")                                                   \
            for (int nt_ = 0; nt_ < 4; ++nt_) {                                 \
                const bf16x8 bv_ = *reinterpret_cast<const bf16x8*>(            \
                    XTB + (size_t)(nt_ * 16 + (lane & 15)) * BKP                \
                        + kw_ * 32 + (lane >> 4) * 8);                          \
                acc[0][nt_] = __builtin_amdgcn_mfma_f32_16x16x32_bf16(          \
                    A[kw_], bv_, acc[0][nt_], 0, 0, 0);                         \
                acc[1][nt_] = __builtin_amdgcn_mfma_f32_16x16x32_bf16(          \
                    A[2 + kw_], bv_, acc[1][nt_], 0, 0, 0);                     \
            }                                                                   \
        }                                                                       \
    } while (0)

// raw barrier: drain LDS only (ds_writes visible), keep global loads in flight
#define BAR() do {                                                              \
        asm volatile("s_waitcnt lgkmcnt(0)" ::: "memory");                      \
        __builtin_amdgcn_s_barrier();                                           \
        __builtin_amdgcn_sched_barrier(0);                                      \
    } while (0)

    float2 rA[8], rB[8];
    bf16x8 aA[4], aB[4];
    STAGE_LOAD(rA, 0);
    STAGE_LOAD(rB, 1);
    LOAD_A(aA, 0);
    LOAD_A(aB, 1);

    for (int itp = 0; itp < 16; ++itp) {
        const int it0 = 2 * itp;
        // even iteration: buffer XT0
        PACK_WRITE(rA, XT0);
        if (it0 + 2 < NITER) STAGE_LOAD(rA, it0 + 2);
        BAR();
        MFMA_PHASE(aA, XT0);
        if (it0 + 2 < NITER) LOAD_A(aA, it0 + 2);
        // odd iteration: buffer XT1
        PACK_WRITE(rB, XT1);
        if (it0 + 3 < NITER) STAGE_LOAD(rB, it0 + 3);
        BAR();
        MFMA_PHASE(aB, XT1);
        if (it0 + 3 < NITER) LOAD_A(aB, it0 + 3);
    }

    __syncthreads();                           // full drain once; XT -> dotsL overlay
    // acc -> dots LDS ; C/D map: col=lane&15, row=4*(lane>>4)+reg (m89-verified)
#pragma unroll
    for (int rt = 0; rt < 2; ++rt)
#pragma unroll
        for (int nt = 0; nt < 4; ++nt)
#pragma unroll
            for (int rr = 0; rr < 4; ++rr)
                dotsL[(size_t)(16 * (2 * w + rt) + 4 * (lane >> 4) + rr) * 66 +
                      nt * 16 + (lane & 15)] = acc[rt][nt][rr];
    xsqp[kc * 64 + 2 * pr] = xs0;
    xsqp[kc * 64 + 2 * pr + 1] = xs1;
    if (tid < MROWS) asq_s[tid] = asq_g[tid];
    __syncthreads();

    // softmax over rows 0..112 per column; wave q handles a row chunk
    const int j = tid & 63;
    const int q = tid >> 6;
    float xsq = 0.f;
#pragma unroll
    for (int g = 0; g < 8; ++g) xsq += xsqp[g * 64 + j];
    const int rbeg = 29 * q;
    const int rend = (rbeg + 29 < KB) ? rbeg + 29 : KB;

    float m = -3.4e38f;
    for (int row = rbeg; row < rend; ++row) {
        const float d2 = asq_s[row] + xsq - 2.f * dotsL[(size_t)row * 66 + j];
        const float L = -sqrtf(fmaxf(d2, 0.f));
        dotsL[(size_t)row * 66 + j] = L;
        m = fmaxf(m, L);
    }
    pm[q * 64 + j] = m;
    __syncthreads();
    const float M = fmaxf(fmaxf(pm[j], pm[64 + j]), fmaxf(pm[128 + j], pm[192 + j]));
    float s = 0.f;
    for (int row = rbeg; row < rend; ++row) s += __expf(dotsL[(size_t)row * 66 + j] - M);
    ps[q * 64 + j] = s;
    __syncthreads();
    const float S = ps[j] + ps[64 + j] + ps[128 + j] + ps[192 + j];
    const float invS = 1.f / S;
    const float xw = dotsL[(size_t)XWROW * 66 + j];   // raw dot row 113 (0 for pad cols)

    const bool jv = (n0 + j) < N;
    float* o0 = out0 + (size_t)b * KB * N + n0 + j;
    for (int row = rbeg; row < rend; ++row) {
        const float a = __expf(dotsL[(size_t)row * 66 + j] - M) * invS;
        if (jv) o0[(size_t)row * N] = a;
        if (row < K) {
            float p = a * xw;
            for (int off = 32; off; off >>= 1) p += __shfl_down(p, off);
            if (j == 0) lpart[((size_t)b * 4 + nt4) * K + row] = p;
        }
    }
}

// ---------------------------------------------------------------------------
// pq_kernel: R[o,k] = (concepts[k]-mod).w_lfc[o,k,:] ; Qs[o,k] = mod.w_lfc[o,k,:]
// ---------------------------------------------------------------------------
__global__ __launch_bounds__(256)
void pq_kernel(const float* __restrict__ wlfc, const float* __restrict__ concepts,
               const float* __restrict__ modulation,
               float* __restrict__ Rm, float* __restrict__ Qs) {
    const int wid = (blockIdx.x * 256 + threadIdx.x) >> 6;
    const int lane = threadIdx.x & 63;
    if (wid >= NCLS * K) return;
    const int o = wid / K;
    const int k = wid % K;
    const float4* wp = reinterpret_cast<const float4*>(wlfc + (size_t)o * CKC + (size_t)k * C);
    const float4* cp = reinterpret_cast<const float4*>(concepts + (size_t)k * C);
    const float4* mp = reinterpret_cast<const float4*>(modulation);
    float s1 = 0.f, s2 = 0.f;
#pragma unroll
    for (int it = 0; it < 8; ++it) {
        const int idx = it * 64 + lane;
        const float4 w4 = wp[idx];
        const float4 c4 = cp[idx];
        const float4 m4 = mp[idx];
        s1 += w4.x * c4.x + w4.y * c4.y + w4.z * c4.z + w4.w * c4.w;
        s2 += w4.x * m4.x + w4.y * m4.y + w4.z * m4.z + w4.w * m4.w;
    }
    for (int off = 32; off; off >>= 1) {
        s1 += __shfl_down(s1, off);
        s2 += __shfl_down(s2, off);
    }
    if (lane == 0) { Rm[wid] = s1 - s2; Qs[wid] = s2; }
}

// ---------------------------------------------------------------------------
// final_kernel: g = sigmoid(sum lpart + b_cfc); label = b_lfc + sum_k g*R + Q
// ---------------------------------------------------------------------------
__global__ __launch_bounds__(256)
void final_kernel(const float* __restrict__ lpart, const float* __restrict__ bcfc,
                  const float* __restrict__ Rm, const float* __restrict__ Qs,
                  const float* __restrict__ blfc,
                  float* __restrict__ out1, float* __restrict__ out2) {
    const int b = blockIdx.x;
    const int tid = threadIdx.x;
    __shared__ float g_s[K];
    if (tid < K) {
        const float* lp = lpart + (size_t)b * 4 * K + tid;
        const float v = lp[0] + lp[K] + lp[2 * K] + lp[3 * K] + bcfc[0];
        const float g = 1.f / (1.f + __expf(-v));
        out1[b * K + tid] = g;
        g_s[tid] = g;
    }
    __syncthreads();
    if (tid < NCLS) {
        float acc = blfc[tid];
        const float* rp = Rm + (size_t)tid * K;
        const float* qp = Qs + (size_t)tid * K;
        for (int k = 0; k < K; ++k) acc = fmaf(g_s[k], rp[k], acc) + qp[k];
        out2[b * NCLS + tid] = acc;
    }
}

extern "C" void kernel_launch(void* const* d_in, const int* in_sizes, int n_in,
                              void* d_out, int out_size, void* d_ws, size_t ws_size,
                              hipStream_t stream) {
    const float* x          = (const float*)d_in[0];
    const float* concepts   = (const float*)d_in[1];
    const float* modulation = (const float*)d_in[2];
    const float* background = (const float*)d_in[3];
    const float* wcfc       = (const float*)d_in[4];
    const float* bcfc       = (const float*)d_in[5];
    const float* wlfc       = (const float*)d_in[6];
    const float* blfc       = (const float*)d_in[7];

    float* out  = (float*)d_out;
    float* out0 = out;
    float* out1 = out + OUT1_OFF;
    float* out2 = out + OUT2_OFF;

    float* ws    = (float*)d_ws;
    float* asq   = ws;                               // 128
    float* lpart = asq + MROWS;                      // 128*4*112 = 57344
    float* Rm    = lpart + (size_t)B * 4 * K;        // 22400
    float* Qs    = Rm + NCLS * K;                    // 22400
    unsigned short* Afrag = (unsigned short*)(Qs + NCLS * K);  // 8*64*64*8 u16 = 512KB

    asq_kernel<<<MROWS, 256, 0, stream>>>(concepts, background, wcfc, asq);
    pack_kernel<<<dim3(8, 64), 64, 0, stream>>>(concepts, background, wcfc, Afrag);
    main_kernel<<<dim3(4, B), 256, 0, stream>>>(x, Afrag, asq, out0, lpart);
    pq_kernel<<<(NCLS * K) / 4, 256, 0, stream>>>(wlfc, concepts, modulation, Rm, Qs);
    final_kernel<<<B, 256, 0, stream>>>(lpart, bcfc, Rm, Qs, blfc, out1, out2);
}